// Round 22
// baseline (452.744 us; speedup 1.0000x reference)
//
#include <hip/hip_runtime.h>

typedef __bf16 bf16x8 __attribute__((ext_vector_type(8)));
typedef __bf16 bf16x4 __attribute__((ext_vector_type(4)));
typedef float f32x4 __attribute__((ext_vector_type(4)));
typedef unsigned short u16x8 __attribute__((ext_vector_type(8)));
typedef unsigned short u16x4 __attribute__((ext_vector_type(4)));

__device__ __forceinline__ unsigned short f2b(float f) {
    union { float f; unsigned int u; } v; v.f = f;
    unsigned int r = v.u + 0x7fffu + ((v.u >> 16) & 1u);
    return (unsigned short)(r >> 16);
}
__device__ __forceinline__ float b2f(unsigned short b) {
    union { unsigned int u; float f; } v; v.u = ((unsigned int)b) << 16;
    return v.f;
}

__device__ __forceinline__ void gll16(const unsigned short* g, unsigned short* l) {
    __builtin_amdgcn_global_load_lds(
        (const __attribute__((address_space(1))) unsigned int*)g,
        (__attribute__((address_space(3))) unsigned int*)l, 16, 0, 0);
}

// ---------------- weight -> MFMA-fragment-major bf16 pack ----------------
__global__ __launch_bounds__(256) void prep_wfrag(
    const float* __restrict__ W, unsigned short* __restrict__ dst, int K, int NN)
{
    int k0 = blockIdx.x * 32, n0 = blockIdx.y * 16;
    int KS = K >> 5;
    size_t fbase = ((size_t)(n0 >> 4) * KS + (k0 >> 5)) * 512;
    for (int p = threadIdx.x; p < 512; p += 256) {
        int e = p & 7, lane = p >> 3;
        int n = lane & 15, k = ((lane >> 4) << 3) + e;
        dst[fbase + p] = f2b(W[(size_t)(k0 + k) * NN + n0 + n]);
    }
}

// ---------------- per-layer Q/K/V weight transpose ----------------
__global__ __launch_bounds__(256) void prep_wT(
    const float* __restrict__ Wq, const float* __restrict__ Wk, const float* __restrict__ Wv,
    unsigned short* __restrict__ wT)
{
    int l = blockIdx.x / 3, w = blockIdx.x % 3;
    const float* src = (w == 0 ? Wq : w == 1 ? Wk : Wv) + (size_t)l * 1024;
    unsigned short* dst = wT + ((size_t)l * 3 + w) * 1024;
    float scale = (w == 0) ? 0.0625f : 1.0f;
    int t = threadIdx.x;
    f32x4 v = *(const f32x4*)&src[t * 4];
    int d = (t * 4) >> 5, j0 = (t * 4) & 31;
    #pragma unroll
    for (int e = 0; e < 4; e++)
        dst[(j0 + e) * 32 + d] = f2b(v[e] * scale);
}

// ---------------- cur = bf16(x + pos_emb[positions]); qb = bf16(q) ----------------
__global__ __launch_bounds__(256) void add_posemb_q(
    const float* __restrict__ x, const int* __restrict__ pos,
    const float* __restrict__ pe, const float* __restrict__ q,
    unsigned short* __restrict__ cur, unsigned short* __restrict__ qb)
{
    size_t row = blockIdx.x;
    int t = threadIdx.x;
    int p = pos[row];
    cur[row * 256 + t] = f2b(x[row * 256 + t] + pe[(size_t)p * 256 + t]);
    qb[row * 256 + t] = f2b(q[row * 256 + t]);
}

// ---------------- fused attention: one block = all 8 heads of one n ----------------
// Per head: projections (MFMA) -> swapped QK^T -> lane-local softmax -> PV.
// Next head's A-fragments preloaded (global->reg) so HBM latency hides under compute.
__global__ __launch_bounds__(384, 2) void attn_kernel(
    const unsigned short* __restrict__ cur, const unsigned short* __restrict__ qb,
    const unsigned short* __restrict__ wT,
    unsigned short* __restrict__ og)
{
    __shared__ __align__(16) unsigned short qs[96 * 40];
    __shared__ __align__(16) unsigned short ks[96 * 40];
    __shared__ __align__(16) unsigned short vs[96 * 32];   // V subtiled for tr_b16

    int n = blockIdx.x;
    int tid = threadIdx.x;
    int wave = tid >> 6, lane = tid & 63;
    int lr = lane & 15, lg = lane >> 4;
    int hiw = lane & 1;

    bf16x8 wq[2], wk[2], wv[2];
    #pragma unroll
    for (int ct = 0; ct < 2; ct++) {
        int o = (ct * 16 + lr) * 32 + lg * 8;
        wq[ct] = *(const bf16x8*)&wT[o];
        wk[ct] = *(const bf16x8*)&wT[1024 + o];
        wv[ct] = *(const bf16x8*)&wT[2048 + o];
    }

    int prow = wave * 16 + lr;
    bool rowok = prow < 90;
    size_t rowbase = ((size_t)(n * 90 + prow)) * 256 + lg * 8;   // + h*32

    bf16x8 aq = {0,0,0,0,0,0,0,0}, ac = {0,0,0,0,0,0,0,0};
    if (rowok) {
        aq = *(const bf16x8*)&qb[rowbase];
        ac = *(const bf16x8*)&cur[rowbase];
    }

    #pragma unroll 1
    for (int h = 0; h < 8; h++) {
        // ---- fused projections for head h (paired-u32 writes, proven layout) ----
        {
            f32x4 zz = {0.f, 0.f, 0.f, 0.f};
            #pragma unroll
            for (int ct = 0; ct < 2; ct++) {
                f32x4 qc = __builtin_amdgcn_mfma_f32_16x16x32_bf16(aq, wq[ct], zz, 0, 0, 0);
                f32x4 kc = __builtin_amdgcn_mfma_f32_16x16x32_bf16(ac, wk[ct], zz, 0, 0, 0);
                f32x4 vc = __builtin_amdgcn_mfma_f32_16x16x32_bf16(ac, wv[ct], zz, 0, 0, 0);
                #pragma unroll
                for (int rr = 0; rr < 4; rr++) {
                    float oq = __shfl_xor(qc[rr], 1);
                    unsigned a16 = f2b(qc[rr]), o16 = f2b(oq);
                    unsigned pk = hiw ? (o16 | (a16 << 16)) : (a16 | (o16 << 16));
                    if ((rr >> 1) == hiw)
                        *(unsigned*)&qs[(wave * 16 + lg * 4 + rr) * 40 + ct * 16 + (lr & ~1)] = pk;

                    float ok = __shfl_xor(kc[rr], 1);
                    a16 = f2b(kc[rr]); o16 = f2b(ok);
                    pk = hiw ? (o16 | (a16 << 16)) : (a16 | (o16 << 16));
                    if ((rr >> 1) == hiw)
                        *(unsigned*)&ks[(wave * 16 + lg * 4 + rr) * 40 + ct * 16 + (lr & ~1)] = pk;

                    float ov = __shfl_xor(vc[rr], 1);
                    a16 = f2b(vc[rr]); o16 = f2b(ov);
                    pk = hiw ? (o16 | (a16 << 16)) : (a16 | (o16 << 16));
                    if ((rr >> 1) == hiw)
                        *(unsigned*)&vs[(wave * 4 + lg) * 128 + ct * 64 + rr * 16 + (lr & ~1)] = pk;
                }
            }
        }
        __syncthreads();   // qs/ks/vs ready

        // ---- preload next head's A-fragments (latency hidden under QK/SM/PV) ----
        bf16x8 aqn = {0,0,0,0,0,0,0,0}, acn = {0,0,0,0,0,0,0,0};
        if (h < 7 && rowok) {
            aqn = *(const bf16x8*)&qb[rowbase + (h + 1) * 32];
            acn = *(const bf16x8*)&cur[rowbase + (h + 1) * 32];
        }

        // ---- swapped QK^T: cs[j] = mfma(K_j, Q) ----
        f32x4 cs[6];
        {
            bf16x8 aqf = *(const bf16x8*)&qs[(wave * 16 + lr) * 40 + lg * 8];
            #pragma unroll
            for (int j = 0; j < 6; j++) {
                bf16x8 bk = *(const bf16x8*)&ks[(j * 16 + lr) * 40 + lg * 8];
                f32x4 z = {0.f, 0.f, 0.f, 0.f};
                cs[j] = __builtin_amdgcn_mfma_f32_16x16x32_bf16(bk, aqf, z, 0, 0, 0);
            }
        }
        #pragma unroll
        for (int rr = 0; rr < 4; rr++)
            if (lg * 4 + rr >= 10) cs[5][rr] = -1e30f;

        // ---- lane-local softmax over k (deferred normalization) ----
        float mx = cs[0][0];
        #pragma unroll
        for (int j = 0; j < 6; j++)
            #pragma unroll
            for (int rr = 0; rr < 4; rr++) mx = fmaxf(mx, cs[j][rr]);
        mx = fmaxf(mx, __shfl_xor(mx, 16));
        mx = fmaxf(mx, __shfl_xor(mx, 32));
        float sum = 0.f;
        #pragma unroll
        for (int j = 0; j < 6; j++)
            #pragma unroll
            for (int rr = 0; rr < 4; rr++) {
                float e = __expf(cs[j][rr] - mx);
                cs[j][rr] = e;
                sum += e;
            }
        sum += __shfl_xor(sum, 16);
        sum += __shfl_xor(sum, 32);
        float inv = 1.f / sum;

        // ---- pack P rows to bf16 pairs (unnormalized) ----
        unsigned pk0[6], pk1[6];
        #pragma unroll
        for (int j = 0; j < 6; j++) {
            pk0[j] = (unsigned)f2b(cs[j][0]) | ((unsigned)f2b(cs[j][1]) << 16);
            pk1[j] = (unsigned)f2b(cs[j][2]) | ((unsigned)f2b(cs[j][3]) << 16);
        }

        // ---- PV: A-fragments gathered via shfl; B via ds_read_b64_tr_b16 from vs ----
        {
            unsigned vbase = (unsigned)(size_t)&vs[0];
            int sel = lg >> 1;
            int base_lo = lr + ((lg & 1) * 2) * 16;
            int base_hi = base_lo + 16;
            f32x4 oc0 = {0.f,0.f,0.f,0.f}, oc1 = {0.f,0.f,0.f,0.f};
            #pragma unroll
            for (int s = 0; s < 3; s++) {
                unsigned A0 = __shfl(pk0[2*s],     base_lo);
                unsigned A1 = __shfl(pk1[2*s],     base_lo);
                unsigned B0 = __shfl(pk0[2*s + 1], base_lo);
                unsigned B1 = __shfl(pk1[2*s + 1], base_lo);
                unsigned C0 = __shfl(pk0[2*s],     base_hi);
                unsigned C1 = __shfl(pk1[2*s],     base_hi);
                unsigned D0 = __shfl(pk0[2*s + 1], base_hi);
                unsigned D1 = __shfl(pk1[2*s + 1], base_hi);
                union { unsigned u[4]; bf16x8 v; } apu;
                apu.u[0] = sel ? B0 : A0;
                apu.u[1] = sel ? B1 : A1;
                apu.u[2] = sel ? D0 : C0;
                apu.u[3] = sel ? D1 : C1;

                unsigned ta = vbase + (unsigned)((8 * s + 2 * lg) * 256) + (unsigned)(lr * 8);
                bf16x4 b0a, b0b, b1a, b1b;
                asm volatile(
                    "ds_read_b64_tr_b16 %0, %4\n\t"
                    "ds_read_b64_tr_b16 %1, %4 offset:256\n\t"
                    "ds_read_b64_tr_b16 %2, %4 offset:128\n\t"
                    "ds_read_b64_tr_b16 %3, %4 offset:384\n\t"
                    "s_waitcnt lgkmcnt(0)"
                    : "=&v"(b0a), "=&v"(b0b), "=&v"(b1a), "=&v"(b1b)
                    : "v"(ta) : "memory");
                __builtin_amdgcn_sched_barrier(0);
                bf16x8 bv0, bv1;
                #pragma unroll
                for (int e = 0; e < 4; e++) {
                    bv0[e] = b0a[e]; bv0[4 + e] = b0b[e];
                    bv1[e] = b1a[e]; bv1[4 + e] = b1b[e];
                }
                oc0 = __builtin_amdgcn_mfma_f32_16x16x32_bf16(apu.v, bv0, oc0, 0, 0, 0);
                oc1 = __builtin_amdgcn_mfma_f32_16x16x32_bf16(apu.v, bv1, oc1, 0, 0, 0);
            }
            #pragma unroll
            for (int rr = 0; rr < 4; rr++) {
                float invr = __shfl(inv, lg * 4 + rr);
                int row = wave * 16 + lg * 4 + rr;
                if (row < 90) {
                    size_t base = ((size_t)(n * 90 + row)) * 256 + h * 32;
                    og[base + lr]      = f2b(oc0[rr] * invr);
                    og[base + 16 + lr] = f2b(oc1[rr] * invr);
                }
            }
        }
        __syncthreads();   // protect LDS before next head's proj writes
        aq = aqn; ac = acn;
    }
}

// ---------------- mega kernel: h = LN(attnout@Wo+bo+qb); cur = LN(relu(h@W1+bf1)@W2+bf2+h) ----------------
// Block = 64 rows, 4 waves. attnout staged in As; h kept in hs (LDS); f1 chunks ping into As.
// All B-fragments direct-to-reg (1-deep xa/xb ping-pong). h never touches HBM.
__global__ __launch_bounds__(256, 2) void wo_ffn_fused(
    const unsigned short* __restrict__ A,      // attn out [R][256]
    const unsigned short* __restrict__ WoFl, const float* __restrict__ bo,
    const unsigned short* __restrict__ qb, const float* __restrict__ g1, const float* __restrict__ b1,
    const unsigned short* __restrict__ W1F, const float* __restrict__ bf1,
    const unsigned short* __restrict__ W2F, const float* __restrict__ bf2,
    const float* __restrict__ g2, const float* __restrict__ b2,
    unsigned short* __restrict__ C)
{
    __shared__ __align__(16) unsigned short As[8 * 2048];   // attnout -> f1 chunks
    __shared__ __align__(16) unsigned short hs[8 * 2048];   // h resident
    __shared__ float ssum[64 * 4], ssq[64 * 4];

    int bx = blockIdx.x;
    bx = (bx & 7) * 90 + (bx >> 3);           // XCD swizzle (grid 720)
    int ra0 = bx * 64;

    int tid = threadIdx.x;
    int wave = tid >> 6, lane = tid & 63;
    int wc = wave;
    int lr = lane & 15, lg = lane >> 4;
    int rsub = lane >> 2, sp = lane & 3;

    // ---- stage attn-out panel (K=256 -> 8 windows, 32KB) ----
    #pragma unroll
    for (int kw = 0; kw < 8; kw++) {
        int r = wave * 16 + rsub;
        int sl = sp ^ ((r >> 1) & 3);
        gll16(&A[(size_t)(ra0 + r) * 256 + kw * 32 + sl * 8], &As[kw * 2048 + wave * 512]);
    }
    asm volatile("s_waitcnt vmcnt(0)" ::: "memory");
    __builtin_amdgcn_s_barrier();
    __builtin_amdgcn_sched_barrier(0);

    // ================= Wo GEMM: acc = attnout @ Wo =================
    {
        f32x4 acc[4][4];
        #pragma unroll
        for (int i = 0; i < 4; i++)
            #pragma unroll
            for (int j = 0; j < 4; j++)
                acc[i][j] = (f32x4){0.f, 0.f, 0.f, 0.f};

        int nt0 = wc * 4;
        bf16x8 xa[4], xb[4];
        #pragma unroll
        for (int j = 0; j < 4; j++)
            xa[j] = *(const bf16x8*)&WoFl[((size_t)(nt0 + j) * 8 + 0) * 512 + lane * 8];
        #pragma unroll
        for (int k2 = 0; k2 < 8; k2 += 2) {
            if (k2 + 1 < 8) {
                #pragma unroll
                for (int j = 0; j < 4; j++)
                    xb[j] = *(const bf16x8*)&WoFl[((size_t)(nt0 + j) * 8 + k2 + 1) * 512 + lane * 8];
            }
            {
                bf16x8 ya[4];
                #pragma unroll
                for (int i = 0; i < 4; i++) {
                    int mm = i * 16 + lr;
                    ya[i] = *(const bf16x8*)&As[k2 * 2048 + mm * 32 + (lg ^ ((mm >> 1) & 3)) * 8];
                }
                #pragma unroll
                for (int i = 0; i < 4; i++)
                    #pragma unroll
                    for (int j = 0; j < 4; j++)
                        acc[i][j] = __builtin_amdgcn_mfma_f32_16x16x32_bf16(xa[j], ya[i], acc[i][j], 0, 0, 0);
            }
            if (k2 + 2 < 8) {
                #pragma unroll
                for (int j = 0; j < 4; j++)
                    xa[j] = *(const bf16x8*)&WoFl[((size_t)(nt0 + j) * 8 + k2 + 2) * 512 + lane * 8];
            }
            {
                bf16x8 ya[4];
                #pragma unroll
                for (int i = 0; i < 4; i++) {
                    int mm = i * 16 + lr;
                    ya[i] = *(const bf16x8*)&As[(k2 + 1) * 2048 + mm * 32 + (lg ^ ((mm >> 1) & 3)) * 8];
                }
                #pragma unroll
                for (int i = 0; i < 4; i++)
                    #pragma unroll
                    for (int j = 0; j < 4; j++)
                        acc[i][j] = __builtin_amdgcn_mfma_f32_16x16x32_bf16(xb[j], ya[i], acc[i][j], 0, 0, 0);
            }
        }

        // ---- LN(acc + bo + qb) -> hs (window layout) ----
        float s1[4] = {0.f,0.f,0.f,0.f}, sq[4] = {0.f,0.f,0.f,0.f};
        #pragma unroll
        for (int i = 0; i < 4; i++) {
            int row = ra0 + i * 16 + lr;
            #pragma unroll
            for (int j = 0; j < 4; j++) {
                int ncol = wc * 64 + j * 16 + lg * 4;
                f32x4 bv = *(const f32x4*)&bo[ncol];
                u16x4 rv = *(const u16x4*)&qb[(size_t)row * 256 + ncol];
                #pragma unroll
                for (int rr = 0; rr < 4; rr++) {
                    acc[i][j][rr] += bv[rr] + b2f(rv[rr]);
                    s1[i] += acc[i][j][rr];
                    sq[i] += acc[i][j][rr] * acc[i][j][rr];
                }
            }
        }
        #pragma unroll
        for (int i = 0; i < 4; i++) {
            s1[i] += __shfl_xor(s1[i], 16);  s1[i] += __shfl_xor(s1[i], 32);
            sq[i] += __shfl_xor(sq[i], 16);  sq[i] += __shfl_xor(sq[i], 32);
            if (lg == 0) {
                int rb = i * 16 + lr;
                ssum[rb * 4 + wc] = s1[i];
                ssq[rb * 4 + wc]  = sq[i];
            }
        }
        __syncthreads();
        #pragma unroll
        for (int i = 0; i < 4; i++) {
            int rb = i * 16 + lr;
            float ts = 0.f, tq = 0.f;
            #pragma unroll
            for (int w = 0; w < 4; w++) { ts += ssum[rb * 4 + w]; tq += ssq[rb * 4 + w]; }
            float mean = ts * (1.f / 256.f);
            float var = tq * (1.f / 256.f) - mean * mean;
            float inv = rsqrtf(var + 1e-5f);
            #pragma unroll
            for (int j = 0; j < 4; j++) {
                int ncol = wc * 64 + j * 16 + lg * 4;
                f32x4 gv = *(const f32x4*)&g1[ncol];
                f32x4 bv = *(const f32x4*)&b1[ncol];
                int row = i * 16 + lr;
                int win = ncol >> 5, cw = ncol & 31;
                int p = (cw >> 3) ^ ((row >> 1) & 3);
                u16x4 ov;
                #pragma unroll
                for (int rr = 0; rr < 4; rr++)
                    ov[rr] = f2b((acc[i][j][rr] - mean) * inv * gv[rr] + bv[rr]);
                *(u16x4*)&hs[win * 2048 + row * 32 + p * 8 + (cw & 7)] = ov;
            }
        }
    }
    __syncthreads();   // hs ready for all waves

    // ================= FFN: acc2 = relu(h@W1+bf1) @ W2 =================
    f32x4 acc2[4][4];
    #pragma unroll
    for (int i = 0; i < 4; i++)
        #pragma unroll
        for (int j = 0; j < 4; j++)
            acc2[i][j] = (f32x4){0.f, 0.f, 0.f, 0.f};

    #pragma unroll 1
    for (int fc = 0; fc < 4; fc++) {
        f32x4 acc1[4][4];
        #pragma unroll
        for (int i = 0; i < 4; i++)
            #pragma unroll
            for (int j = 0; j < 4; j++)
                acc1[i][j] = (f32x4){0.f, 0.f, 0.f, 0.f};

        int ntb1 = fc * 16 + wc * 4;
        bf16x8 xa[4], xb[4];
        #pragma unroll
        for (int j = 0; j < 4; j++)
            xa[j] = *(const bf16x8*)&W1F[((size_t)(ntb1 + j) * 8 + 0) * 512 + lane * 8];
        #pragma unroll
        for (int k2 = 0; k2 < 8; k2 += 2) {
            if (k2 + 1 < 8) {
                #pragma unroll
                for (int j = 0; j < 4; j++)
                    xb[j] = *(const bf16x8*)&W1F[((size_t)(ntb1 + j) * 8 + k2 + 1) * 512 + lane * 8];
            }
            {
                bf16x8 ya[4];
                #pragma unroll
                for (int i = 0; i < 4; i++) {
                    int mm = i * 16 + lr;
                    ya[i] = *(const bf16x8*)&hs[k2 * 2048 + mm * 32 + (lg ^ ((mm >> 1) & 3)) * 8];
                }
                #pragma unroll
                for (int i = 0; i < 4; i++)
                    #pragma unroll
                    for (int j = 0; j < 4; j++)
                        acc1[i][j] = __builtin_amdgcn_mfma_f32_16x16x32_bf16(xa[j], ya[i], acc1[i][j], 0, 0, 0);
            }
            if (k2 + 2 < 8) {
                #pragma unroll
                for (int j = 0; j < 4; j++)
                    xa[j] = *(const bf16x8*)&W1F[((size_t)(ntb1 + j) * 8 + k2 + 2) * 512 + lane * 8];
            }
            {
                bf16x8 ya[4];
                #pragma unroll
                for (int i = 0; i < 4; i++) {
                    int mm = i * 16 + lr;
                    ya[i] = *(const bf16x8*)&hs[(k2 + 1) * 2048 + mm * 32 + (lg ^ ((mm >> 1) & 3)) * 8];
                }
                #pragma unroll
                for (int i = 0; i < 4; i++)
                    #pragma unroll
                    for (int j = 0; j < 4; j++)
                        acc1[i][j] = __builtin_amdgcn_mfma_f32_16x16x32_bf16(xb[j], ya[i], acc1[i][j], 0, 0, 0);
            }
        }

        // relu + bias -> As (window layout); As' attnout contents are dead
        __syncthreads();
        #pragma unroll
        for (int i = 0; i < 4; i++) {
            int row = i * 16 + lr;
            #pragma unroll
            for (int j = 0; j < 4; j++) {
                int ncol = wc * 64 + j * 16 + lg * 4;
                f32x4 bv = *(const f32x4*)&bf1[fc * 256 + ncol];
                int win = ncol >> 5, cw = ncol & 31;
                int p = (cw >> 3) ^ ((row >> 1) & 3);
                u16x4 ov;
                #pragma unroll
                for (int rr = 0; rr < 4; rr++)
                    ov[rr] = f2b(fmaxf(acc1[i][j][rr] + bv[rr], 0.f));
                *(u16x4*)&As[win * 2048 + row * 32 + p * 8 + (cw & 7)] = ov;
            }
        }
        __syncthreads();

        // FFN2 partial: acc2 += f1_chunk @ W2[fc]
        int ntb2 = wc * 4;
        #pragma unroll
        for (int j = 0; j < 4; j++)
            xa[j] = *(const bf16x8*)&W2F[((size_t)(ntb2 + j) * 32 + fc * 8 + 0) * 512 + lane * 8];
        #pragma unroll
        for (int k2 = 0; k2 < 8; k2 += 2) {
            if (k2 + 1 < 8) {
                #pragma unroll
                for (int j = 0; j < 4; j++)
                    xb[j] = *(const bf16x8*)&W2F[((size_t)(ntb2 + j) * 32 + fc * 8 + k2 + 1) * 512 + lane * 8];
            }
            {
                bf16x8 ya[4];
                #pragma unroll
                for (int i = 0; i < 4; i++) {
                    int mm = i * 16 + lr;
                    ya[i] = *(const bf16x8*)&As[k2 * 2048 + mm * 32 + (lg ^ ((mm >> 1) & 3)) * 8];
                }
                #pragma unroll
                for (int i = 0; i < 4; i++)
                    #pragma unroll
                    for (int j = 0; j < 4; j++)
                        acc2[i][j] = __builtin_amdgcn_mfma_f32_16x16x32_bf16(xa[j], ya[i], acc2[i][j], 0, 0, 0);
            }
            if (k2 + 2 < 8) {
                #pragma unroll
                for (int j = 0; j < 4; j++)
                    xa[j] = *(const bf16x8*)&W2F[((size_t)(ntb2 + j) * 32 + fc * 8 + k2 + 2) * 512 + lane * 8];
            }
            {
                bf16x8 ya[4];
                #pragma unroll
                for (int i = 0; i < 4; i++) {
                    int mm = i * 16 + lr;
                    ya[i] = *(const bf16x8*)&As[(k2 + 1) * 2048 + mm * 32 + (lg ^ ((mm >> 1) & 3)) * 8];
                }
                #pragma unroll
                for (int i = 0; i < 4; i++)
                    #pragma unroll
                    for (int j = 0; j < 4; j++)
                        acc2[i][j] = __builtin_amdgcn_mfma_f32_16x16x32_bf16(xb[j], ya[i], acc2[i][j], 0, 0, 0);
            }
        }
    }
    __syncthreads();

    // ---- final LN: cur = LN(acc2 + bf2 + h)*g2 + b2, residual h from hs ----
    float s1[4] = {0.f,0.f,0.f,0.f}, sq[4] = {0.f,0.f,0.f,0.f};
    #pragma unroll
    for (int i = 0; i < 4; i++) {
        int row = i * 16 + lr;
        #pragma unroll
        for (int j = 0; j < 4; j++) {
            int ncol = wc * 64 + j * 16 + lg * 4;
            f32x4 bv = *(const f32x4*)&bf2[ncol];
            int win = ncol >> 5, cw = ncol & 31;
            int p = (cw >> 3) ^ ((row >> 1) & 3);
            u16x4 rv = *(const u16x4*)&hs[win * 2048 + row * 32 + p * 8 + (cw & 7)];
            #pragma unroll
            for (int rr = 0; rr < 4; rr++) {
                acc2[i][j][rr] += bv[rr] + b2f(rv[rr]);
                s1[i] += acc2[i][j][rr];
                sq[i] += acc2[i][j][rr] * acc2[i][j][rr];
            }
        }
    }
    #pragma unroll
    for (int i = 0; i < 4; i++) {
        s1[i] += __shfl_xor(s1[i], 16);  s1[i] += __shfl_xor(s1[i], 32);
        sq[i] += __shfl_xor(sq[i], 16);  sq[i] += __shfl_xor(sq[i], 32);
        if (lg == 0) {
            int rb = i * 16 + lr;
            ssum[rb * 4 + wc] = s1[i];
            ssq[rb * 4 + wc]  = sq[i];
        }
    }
    __syncthreads();
    #pragma unroll
    for (int i = 0; i < 4; i++) {
        int rb = i * 16 + lr;
        float ts = 0.f, tq = 0.f;
        #pragma unroll
        for (int w = 0; w < 4; w++) { ts += ssum[rb * 4 + w]; tq += ssq[rb * 4 + w]; }
        float mean = ts * (1.f / 256.f);
        float var = tq * (1.f / 256.f) - mean * mean;
        float inv = rsqrtf(var + 1e-5f);
        int row = ra0 + rb;
        #pragma unroll
        for (int j = 0; j < 4; j++) {
            int ncol = wc * 64 + j * 16 + lg * 4;
            f32x4 gv = *(const f32x4*)&g2[ncol];
            f32x4 bv = *(const f32x4*)&b2[ncol];
            u16x4 ov;
            #pragma unroll
            for (int rr = 0; rr < 4; rr++)
                ov[rr] = f2b((acc2[i][j][rr] - mean) * inv * gv[rr] + bv[rr]);
            *(u16x4*)&C[(size_t)row * 256 + ncol] = ov;
        }
    }
}

// ---------------- classifier head ----------------
__global__ __launch_bounds__(256) void classifier(
    const unsigned short* __restrict__ xin,
    const float* __restrict__ Wc1, const float* __restrict__ bc1,
    const float* __restrict__ Wc2, const float* __restrict__ bc2,
    const float* __restrict__ Wc3, const float* __restrict__ bc3,
    float* __restrict__ out)
{
    __shared__ float w1[256][9];
    __shared__ float w2[64], b2s[8], w3[16], b3s[2], b1s[8];
    int t = threadIdx.x;
    #pragma unroll
    for (int i = 0; i < 8; i++) {
        int idx = t + i * 256;
        w1[idx >> 3][idx & 7] = Wc1[idx];
    }
    if (t < 64) w2[t] = Wc2[t];
    if (t < 16) w3[t] = Wc3[t];
    if (t < 8) { b2s[t] = bc2[t]; b1s[t] = bc1[t]; }
    if (t < 2) b3s[t] = bc3[t];
    __syncthreads();
    int g = t >> 3, m = t & 7;
    size_t row = (size_t)blockIdx.x * 32 + g;
    float z[8] = {0.f,0.f,0.f,0.f,0.f,0.f,0.f,0.f};
    const unsigned short* xr = xin + row * 256 + m * 32;
    #pragma unroll
    for (int cidx = 0; cidx < 4; cidx++) {
        u16x8 xv = *(const u16x8*)&xr[cidx * 8];
        #pragma unroll
        for (int e = 0; e < 8; e++) {
            float xf = b2f(xv[e]);
            int ei = m * 32 + cidx * 8 + e;
            #pragma unroll
            for (int j = 0; j < 8; j++) z[j] = fmaf(xf, w1[ei][j], z[j]);
        }
    }
    #pragma unroll
    for (int d = 1; d < 8; d <<= 1)
        #pragma unroll
        for (int j = 0; j < 8; j++) z[j] += __shfl_xor(z[j], d);
    float z1[8], z2[8];
    #pragma unroll
    for (int j = 0; j < 8; j++) z1[j] = tanhf(z[j] + b1s[j]);
    #pragma unroll
    for (int j2 = 0; j2 < 8; j2++) {
        float sacc = b2s[j2];
        #pragma unroll
        for (int j = 0; j < 8; j++) sacc = fmaf(z1[j], w2[j * 8 + j2], sacc);
        z2[j2] = tanhf(sacc);
    }
    if (m < 2) {
        float sacc = b3s[m];
        #pragma unroll
        for (int j = 0; j < 8; j++) sacc = fmaf(z2[j], w3[j * 2 + m], sacc);
        out[row * 2 + m] = 1.f / (1.f + __expf(-sacc));
    }
}

extern "C" void kernel_launch(void* const* d_in, const int* in_sizes, int n_in,
                              void* d_out, int out_size, void* d_ws, size_t ws_size,
                              hipStream_t stream) {
    const float* x        = (const float*)d_in[0];
    const float* q        = (const float*)d_in[1];
    const int*   positions= (const int*)d_in[2];
    const float* pos_emb  = (const float*)d_in[3];
    const float* Wq       = (const float*)d_in[4];
    const float* Wk       = (const float*)d_in[5];
    const float* Wv       = (const float*)d_in[6];
    const float* Wo       = (const float*)d_in[7];
    const float* bo       = (const float*)d_in[8];
    const float* g1       = (const float*)d_in[9];
    const float* b1       = (const float*)d_in[10];
    const float* g2       = (const float*)d_in[11];
    const float* b2       = (const float*)d_in[12];
    const float* Wf1      = (const float*)d_in[13];
    const float* bf1      = (const float*)d_in[14];
    const float* Wf2      = (const float*)d_in[15];
    const float* bf2      = (const float*)d_in[16];
    const float* Wc1      = (const float*)d_in[17];
    const float* bc1      = (const float*)d_in[18];
    const float* Wc2      = (const float*)d_in[19];
    const float* bc2      = (const float*)d_in[20];
    const float* Wc3      = (const float*)d_in[21];
    const float* bc3      = (const float*)d_in[22];
    float* out = (float*)d_out;

    const int R = 512 * 90;          // 46080 token rows
    char* ws = (char*)d_ws;
    size_t off = 0;
    auto alloc = [&](size_t bytes) -> void* {
        void* p = ws + off;
        off += (bytes + 255) & ~(size_t)255;
        return p;
    };
    unsigned short* cur = (unsigned short*)alloc((size_t)R * 256 * 2);
    unsigned short* qb  = (unsigned short*)alloc((size_t)R * 256 * 2);
    unsigned short* qho = (unsigned short*)alloc((size_t)R * 256 * 2);  // attn out
    unsigned short* WoF = (unsigned short*)alloc((size_t)3 * 256 * 256 * 2);
    unsigned short* W1F = (unsigned short*)alloc((size_t)3 * 1024 * 256 * 2);
    unsigned short* W2F = (unsigned short*)alloc((size_t)3 * 256 * 1024 * 2);
    unsigned short* WTqkv = (unsigned short*)alloc((size_t)3 * 3 * 1024 * 2);

    for (int l = 0; l < 3; l++) {
        prep_wfrag<<<dim3(8, 16),  256, 0, stream>>>(Wo  + (size_t)l*256*256,  WoF + (size_t)l*256*256,  256, 256);
        prep_wfrag<<<dim3(8, 64),  256, 0, stream>>>(Wf1 + (size_t)l*256*1024, W1F + (size_t)l*1024*256, 256, 1024);
        prep_wfrag<<<dim3(32, 16), 256, 0, stream>>>(Wf2 + (size_t)l*1024*256, W2F + (size_t)l*256*1024, 1024, 256);
    }
    prep_wT<<<9, 256, 0, stream>>>(Wq, Wk, Wv, WTqkv);
    add_posemb_q<<<R, 256, 0, stream>>>(x, positions, pos_emb, q, cur, qb);

    for (int l = 0; l < 3; l++) {
        attn_kernel<<<512, 384, 0, stream>>>(cur, qb, WTqkv + (size_t)l * 3 * 1024, qho);
        wo_ffn_fused<<<dim3(720), 256, 0, stream>>>(
            qho, WoF + (size_t)l*256*256, bo + l*256,
            qb, g1 + l*256, b1 + l*256,
            W1F + (size_t)l*1024*256, bf1 + l*1024,
            W2F + (size_t)l*256*1024, bf2 + l*256,
            g2 + l*256, b2 + l*256, cur);
    }
    classifier<<<R / 32, 256, 0, stream>>>(cur, Wc1, bc1, Wc2, bc2, Wc3, bc3, out);
}

// Round 23
// 438.874 us; speedup vs baseline: 1.0316x; 1.0316x over previous
//
#include <hip/hip_runtime.h>

typedef __bf16 bf16x8 __attribute__((ext_vector_type(8)));
typedef __bf16 bf16x4 __attribute__((ext_vector_type(4)));
typedef float f32x4 __attribute__((ext_vector_type(4)));
typedef unsigned short u16x8 __attribute__((ext_vector_type(8)));
typedef unsigned short u16x4 __attribute__((ext_vector_type(4)));

__device__ __forceinline__ unsigned short f2b(float f) {
    union { float f; unsigned int u; } v; v.f = f;
    unsigned int r = v.u + 0x7fffu + ((v.u >> 16) & 1u);
    return (unsigned short)(r >> 16);
}
__device__ __forceinline__ float b2f(unsigned short b) {
    union { unsigned int u; float f; } v; v.u = ((unsigned int)b) << 16;
    return v.f;
}

__device__ __forceinline__ void gll16(const unsigned short* g, unsigned short* l) {
    __builtin_amdgcn_global_load_lds(
        (const __attribute__((address_space(1))) unsigned int*)g,
        (__attribute__((address_space(3))) unsigned int*)l, 16, 0, 0);
}

// ---------------- weight -> MFMA-fragment-major bf16 pack ----------------
__global__ __launch_bounds__(256) void prep_wfrag(
    const float* __restrict__ W, unsigned short* __restrict__ dst, int K, int NN)
{
    int k0 = blockIdx.x * 32, n0 = blockIdx.y * 16;
    int KS = K >> 5;
    size_t fbase = ((size_t)(n0 >> 4) * KS + (k0 >> 5)) * 512;
    for (int p = threadIdx.x; p < 512; p += 256) {
        int e = p & 7, lane = p >> 3;
        int n = lane & 15, k = ((lane >> 4) << 3) + e;
        dst[fbase + p] = f2b(W[(size_t)(k0 + k) * NN + n0 + n]);
    }
}

// ---------------- per-layer Q/K/V weight transpose ----------------
__global__ __launch_bounds__(256) void prep_wT(
    const float* __restrict__ Wq, const float* __restrict__ Wk, const float* __restrict__ Wv,
    unsigned short* __restrict__ wT)
{
    int l = blockIdx.x / 3, w = blockIdx.x % 3;
    const float* src = (w == 0 ? Wq : w == 1 ? Wk : Wv) + (size_t)l * 1024;
    unsigned short* dst = wT + ((size_t)l * 3 + w) * 1024;
    float scale = (w == 0) ? 0.0625f : 1.0f;
    int t = threadIdx.x;
    f32x4 v = *(const f32x4*)&src[t * 4];
    int d = (t * 4) >> 5, j0 = (t * 4) & 31;
    #pragma unroll
    for (int e = 0; e < 4; e++)
        dst[(j0 + e) * 32 + d] = f2b(v[e] * scale);
}

// ---------------- cur = bf16(x + pos_emb[positions]); qb = bf16(q) ----------------
__global__ __launch_bounds__(256) void add_posemb_q(
    const float* __restrict__ x, const int* __restrict__ pos,
    const float* __restrict__ pe, const float* __restrict__ q,
    unsigned short* __restrict__ cur, unsigned short* __restrict__ qb)
{
    size_t row = blockIdx.x;
    int t = threadIdx.x;
    int p = pos[row];
    cur[row * 256 + t] = f2b(x[row * 256 + t] + pe[(size_t)p * 256 + t]);
    qb[row * 256 + t] = f2b(q[row * 256 + t]);
}

// ---------------- fused attention per (n,h): projections + softmax(QK^T)V ----------------
// Swapped QK^T: cs[j] = mfma(K_j, Q) -> lane (lr,lg) holds P[q=wave*16+lr][k=j*16+lg*4+rr].
// Softmax fully lane-local (+2 shfls); P kept in registers; single barrier.
__global__ __launch_bounds__(384, 2) void attn_kernel(
    const unsigned short* __restrict__ cur, const unsigned short* __restrict__ qb,
    const unsigned short* __restrict__ wT,
    unsigned short* __restrict__ og)
{
    __shared__ __align__(16) unsigned short qs[96 * 40];
    __shared__ __align__(16) unsigned short ks[96 * 40];
    __shared__ __align__(16) unsigned short vs[96 * 32];   // V subtiled for tr_b16

    int nh = blockIdx.x;
    int n = nh >> 3, h = nh & 7;
    int tid = threadIdx.x;
    int wave = tid >> 6, lane = tid & 63;
    int lr = lane & 15, lg = lane >> 4;
    int hiw = lane & 1;

    bf16x8 wq[2], wk[2], wv[2];
    #pragma unroll
    for (int ct = 0; ct < 2; ct++) {
        int o = (ct * 16 + lr) * 32 + lg * 8;
        wq[ct] = *(const bf16x8*)&wT[o];
        wk[ct] = *(const bf16x8*)&wT[1024 + o];
        wv[ct] = *(const bf16x8*)&wT[2048 + o];
    }

    // ---- fused projections (paired-u32 writes, proven layout) ----
    {
        int tile = wave;
        int row = tile * 16 + lr;
        bf16x8 aq = {0,0,0,0,0,0,0,0}, ac = {0,0,0,0,0,0,0,0};
        if (row < 90) {
            size_t base = ((size_t)(n * 90 + row)) * 256 + h * 32 + lg * 8;
            aq = *(const bf16x8*)&qb[base];
            ac = *(const bf16x8*)&cur[base];
        }
        f32x4 zz = {0.f, 0.f, 0.f, 0.f};
        #pragma unroll
        for (int ct = 0; ct < 2; ct++) {
            f32x4 qc = __builtin_amdgcn_mfma_f32_16x16x32_bf16(aq, wq[ct], zz, 0, 0, 0);
            f32x4 kc = __builtin_amdgcn_mfma_f32_16x16x32_bf16(ac, wk[ct], zz, 0, 0, 0);
            f32x4 vc = __builtin_amdgcn_mfma_f32_16x16x32_bf16(ac, wv[ct], zz, 0, 0, 0);
            #pragma unroll
            for (int rr = 0; rr < 4; rr++) {
                float oq = __shfl_xor(qc[rr], 1);
                unsigned a16 = f2b(qc[rr]), o16 = f2b(oq);
                unsigned pk = hiw ? (o16 | (a16 << 16)) : (a16 | (o16 << 16));
                if ((rr >> 1) == hiw)
                    *(unsigned*)&qs[(tile * 16 + lg * 4 + rr) * 40 + ct * 16 + (lr & ~1)] = pk;

                float ok = __shfl_xor(kc[rr], 1);
                a16 = f2b(kc[rr]); o16 = f2b(ok);
                pk = hiw ? (o16 | (a16 << 16)) : (a16 | (o16 << 16));
                if ((rr >> 1) == hiw)
                    *(unsigned*)&ks[(tile * 16 + lg * 4 + rr) * 40 + ct * 16 + (lr & ~1)] = pk;

                float ov = __shfl_xor(vc[rr], 1);
                a16 = f2b(vc[rr]); o16 = f2b(ov);
                pk = hiw ? (o16 | (a16 << 16)) : (a16 | (o16 << 16));
                if ((rr >> 1) == hiw)
                    *(unsigned*)&vs[(tile * 4 + lg) * 128 + ct * 64 + rr * 16 + (lr & ~1)] = pk;
            }
        }
    }
    __syncthreads();   // ONLY barrier: qs/ks/vs ready

    // ---- swapped QK^T: cs[j] = mfma(K_j, Q) ----
    f32x4 cs[6];
    {
        bf16x8 aq = *(const bf16x8*)&qs[(wave * 16 + lr) * 40 + lg * 8];
        #pragma unroll
        for (int j = 0; j < 6; j++) {
            bf16x8 bk = *(const bf16x8*)&ks[(j * 16 + lr) * 40 + lg * 8];
            f32x4 z = {0.f, 0.f, 0.f, 0.f};
            cs[j] = __builtin_amdgcn_mfma_f32_16x16x32_bf16(bk, aq, z, 0, 0, 0);
        }
    }
    // mask invalid k (j=5, k=80+lg*4+rr >= 90)
    #pragma unroll
    for (int rr = 0; rr < 4; rr++)
        if (lg * 4 + rr >= 10) cs[5][rr] = -1e30f;

    // ---- lane-local softmax over k (deferred normalization) ----
    float mx = cs[0][0];
    #pragma unroll
    for (int j = 0; j < 6; j++)
        #pragma unroll
        for (int rr = 0; rr < 4; rr++) mx = fmaxf(mx, cs[j][rr]);
    mx = fmaxf(mx, __shfl_xor(mx, 16));
    mx = fmaxf(mx, __shfl_xor(mx, 32));
    float sum = 0.f;
    #pragma unroll
    for (int j = 0; j < 6; j++)
        #pragma unroll
        for (int rr = 0; rr < 4; rr++) {
            float e = __expf(cs[j][rr] - mx);
            cs[j][rr] = e;
            sum += e;
        }
    sum += __shfl_xor(sum, 16);
    sum += __shfl_xor(sum, 32);
    float inv = 1.f / sum;

    // ---- pack P rows to bf16 pairs (unnormalized) ----
    unsigned pk0[6], pk1[6];
    #pragma unroll
    for (int j = 0; j < 6; j++) {
        pk0[j] = (unsigned)f2b(cs[j][0]) | ((unsigned)f2b(cs[j][1]) << 16);
        pk1[j] = (unsigned)f2b(cs[j][2]) | ((unsigned)f2b(cs[j][3]) << 16);
    }

    // ---- PV: A-fragments gathered via shfl; B via ds_read_b64_tr_b16 from vs ----
    {
        unsigned vbase = (unsigned)(size_t)&vs[0];
        int sel = lg >> 1;
        int base_lo = lr + ((lg & 1) * 2) * 16;
        int base_hi = base_lo + 16;
        f32x4 oc0 = {0.f,0.f,0.f,0.f}, oc1 = {0.f,0.f,0.f,0.f};
        #pragma unroll
        for (int s = 0; s < 3; s++) {
            // gather ap: j = 2s + (lg>>1); rr=e&3; src lane = lr + ((lg&1)*2 + (e>>2))*16
            unsigned A0 = __shfl(pk0[2*s],     base_lo);
            unsigned A1 = __shfl(pk1[2*s],     base_lo);
            unsigned B0 = __shfl(pk0[2*s + 1], base_lo);
            unsigned B1 = __shfl(pk1[2*s + 1], base_lo);
            unsigned C0 = __shfl(pk0[2*s],     base_hi);
            unsigned C1 = __shfl(pk1[2*s],     base_hi);
            unsigned D0 = __shfl(pk0[2*s + 1], base_hi);
            unsigned D1 = __shfl(pk1[2*s + 1], base_hi);
            union { unsigned u[4]; bf16x8 v; } apu;
            apu.u[0] = sel ? B0 : A0;
            apu.u[1] = sel ? B1 : A1;
            apu.u[2] = sel ? D0 : C0;
            apu.u[3] = sel ? D1 : C1;

            unsigned ta = vbase + (unsigned)((8 * s + 2 * lg) * 256) + (unsigned)(lr * 8);
            bf16x4 b0a, b0b, b1a, b1b;
            asm volatile(
                "ds_read_b64_tr_b16 %0, %4\n\t"
                "ds_read_b64_tr_b16 %1, %4 offset:256\n\t"
                "ds_read_b64_tr_b16 %2, %4 offset:128\n\t"
                "ds_read_b64_tr_b16 %3, %4 offset:384\n\t"
                "s_waitcnt lgkmcnt(0)"
                : "=&v"(b0a), "=&v"(b0b), "=&v"(b1a), "=&v"(b1b)
                : "v"(ta) : "memory");
            __builtin_amdgcn_sched_barrier(0);
            bf16x8 bv0, bv1;
            #pragma unroll
            for (int e = 0; e < 4; e++) {
                bv0[e] = b0a[e]; bv0[4 + e] = b0b[e];
                bv1[e] = b1a[e]; bv1[4 + e] = b1b[e];
            }
            oc0 = __builtin_amdgcn_mfma_f32_16x16x32_bf16(apu.v, bv0, oc0, 0, 0, 0);
            oc1 = __builtin_amdgcn_mfma_f32_16x16x32_bf16(apu.v, bv1, oc1, 0, 0, 0);
        }
        #pragma unroll
        for (int rr = 0; rr < 4; rr++) {
            float invr = __shfl(inv, lg * 4 + rr);
            int row = wave * 16 + lg * 4 + rr;
            if (row < 90) {
                size_t base = ((size_t)(n * 90 + row)) * 256 + h * 32;
                og[base + lr]      = f2b(oc0[rr] * invr);
                og[base + 16 + lr] = f2b(oc1[rr] * invr);
            }
        }
    }
}

// ---------------- mega kernel: h = LN(attnout@Wo+bo+qb); cur = LN(relu(h@W1+bf1)@W2+bf2+h) ----------------
// Block = 64 rows, 4 waves. attnout staged in As; h kept in hs (LDS); f1 chunks ping into As.
// All B-fragments direct-to-reg (1-deep xa/xb ping-pong). h never touches HBM.
__global__ __launch_bounds__(256, 2) void wo_ffn_fused(
    const unsigned short* __restrict__ A,      // attn out [R][256]
    const unsigned short* __restrict__ WoFl, const float* __restrict__ bo,
    const unsigned short* __restrict__ qb, const float* __restrict__ g1, const float* __restrict__ b1,
    const unsigned short* __restrict__ W1F, const float* __restrict__ bf1,
    const unsigned short* __restrict__ W2F, const float* __restrict__ bf2,
    const float* __restrict__ g2, const float* __restrict__ b2,
    unsigned short* __restrict__ C)
{
    __shared__ __align__(16) unsigned short As[8 * 2048];   // attnout -> f1 chunks
    __shared__ __align__(16) unsigned short hs[8 * 2048];   // h resident
    __shared__ float ssum[64 * 4], ssq[64 * 4];

    int bx = blockIdx.x;
    bx = (bx & 7) * 90 + (bx >> 3);           // XCD swizzle (grid 720)
    int ra0 = bx * 64;

    int tid = threadIdx.x;
    int wave = tid >> 6, lane = tid & 63;
    int wc = wave;
    int lr = lane & 15, lg = lane >> 4;
    int rsub = lane >> 2, sp = lane & 3;

    // ---- stage attn-out panel (K=256 -> 8 windows, 32KB) ----
    #pragma unroll
    for (int kw = 0; kw < 8; kw++) {
        int r = wave * 16 + rsub;
        int sl = sp ^ ((r >> 1) & 3);
        gll16(&A[(size_t)(ra0 + r) * 256 + kw * 32 + sl * 8], &As[kw * 2048 + wave * 512]);
    }
    asm volatile("s_waitcnt vmcnt(0)" ::: "memory");
    __builtin_amdgcn_s_barrier();
    __builtin_amdgcn_sched_barrier(0);

    // ================= Wo GEMM: acc = attnout @ Wo =================
    {
        f32x4 acc[4][4];
        #pragma unroll
        for (int i = 0; i < 4; i++)
            #pragma unroll
            for (int j = 0; j < 4; j++)
                acc[i][j] = (f32x4){0.f, 0.f, 0.f, 0.f};

        int nt0 = wc * 4;
        bf16x8 xa[4], xb[4];
        #pragma unroll
        for (int j = 0; j < 4; j++)
            xa[j] = *(const bf16x8*)&WoFl[((size_t)(nt0 + j) * 8 + 0) * 512 + lane * 8];
        #pragma unroll
        for (int k2 = 0; k2 < 8; k2 += 2) {
            if (k2 + 1 < 8) {
                #pragma unroll
                for (int j = 0; j < 4; j++)
                    xb[j] = *(const bf16x8*)&WoFl[((size_t)(nt0 + j) * 8 + k2 + 1) * 512 + lane * 8];
            }
            {
                bf16x8 ya[4];
                #pragma unroll
                for (int i = 0; i < 4; i++) {
                    int mm = i * 16 + lr;
                    ya[i] = *(const bf16x8*)&As[k2 * 2048 + mm * 32 + (lg ^ ((mm >> 1) & 3)) * 8];
                }
                #pragma unroll
                for (int i = 0; i < 4; i++)
                    #pragma unroll
                    for (int j = 0; j < 4; j++)
                        acc[i][j] = __builtin_amdgcn_mfma_f32_16x16x32_bf16(xa[j], ya[i], acc[i][j], 0, 0, 0);
            }
            if (k2 + 2 < 8) {
                #pragma unroll
                for (int j = 0; j < 4; j++)
                    xa[j] = *(const bf16x8*)&WoFl[((size_t)(nt0 + j) * 8 + k2 + 2) * 512 + lane * 8];
            }
            {
                bf16x8 ya[4];
                #pragma unroll
                for (int i = 0; i < 4; i++) {
                    int mm = i * 16 + lr;
                    ya[i] = *(const bf16x8*)&As[(k2 + 1) * 2048 + mm * 32 + (lg ^ ((mm >> 1) & 3)) * 8];
                }
                #pragma unroll
                for (int i = 0; i < 4; i++)
                    #pragma unroll
                    for (int j = 0; j < 4; j++)
                        acc[i][j] = __builtin_amdgcn_mfma_f32_16x16x32_bf16(xb[j], ya[i], acc[i][j], 0, 0, 0);
            }
        }

        // ---- LN(acc + bo + qb) -> hs (window layout) ----
        float s1[4] = {0.f,0.f,0.f,0.f}, sq[4] = {0.f,0.f,0.f,0.f};
        #pragma unroll
        for (int i = 0; i < 4; i++) {
            int row = ra0 + i * 16 + lr;
            #pragma unroll
            for (int j = 0; j < 4; j++) {
                int ncol = wc * 64 + j * 16 + lg * 4;
                f32x4 bv = *(const f32x4*)&bo[ncol];
                u16x4 rv = *(const u16x4*)&qb[(size_t)row * 256 + ncol];
                #pragma unroll
                for (int rr = 0; rr < 4; rr++) {
                    acc[i][j][rr] += bv[rr] + b2f(rv[rr]);
                    s1[i] += acc[i][j][rr];
                    sq[i] += acc[i][j][rr] * acc[i][j][rr];
                }
            }
        }
        #pragma unroll
        for (int i = 0; i < 4; i++) {
            s1[i] += __shfl_xor(s1[i], 16);  s1[i] += __shfl_xor(s1[i], 32);
            sq[i] += __shfl_xor(sq[i], 16);  sq[i] += __shfl_xor(sq[i], 32);
            if (lg == 0) {
                int rb = i * 16 + lr;
                ssum[rb * 4 + wc] = s1[i];
                ssq[rb * 4 + wc]  = sq[i];
            }
        }
        __syncthreads();
        #pragma unroll
        for (int i = 0; i < 4; i++) {
            int rb = i * 16 + lr;
            float ts = 0.f, tq = 0.f;
            #pragma unroll
            for (int w = 0; w < 4; w++) { ts += ssum[rb * 4 + w]; tq += ssq[rb * 4 + w]; }
            float mean = ts * (1.f / 256.f);
            float var = tq * (1.f / 256.f) - mean * mean;
            float inv = rsqrtf(var + 1e-5f);
            #pragma unroll
            for (int j = 0; j < 4; j++) {
                int ncol = wc * 64 + j * 16 + lg * 4;
                f32x4 gv = *(const f32x4*)&g1[ncol];
                f32x4 bv = *(const f32x4*)&b1[ncol];
                int row = i * 16 + lr;
                int win = ncol >> 5, cw = ncol & 31;
                int p = (cw >> 3) ^ ((row >> 1) & 3);
                u16x4 ov;
                #pragma unroll
                for (int rr = 0; rr < 4; rr++)
                    ov[rr] = f2b((acc[i][j][rr] - mean) * inv * gv[rr] + bv[rr]);
                *(u16x4*)&hs[win * 2048 + row * 32 + p * 8 + (cw & 7)] = ov;
            }
        }
    }
    __syncthreads();   // hs ready for all waves

    // ================= FFN: acc2 = relu(h@W1+bf1) @ W2 =================
    f32x4 acc2[4][4];
    #pragma unroll
    for (int i = 0; i < 4; i++)
        #pragma unroll
        for (int j = 0; j < 4; j++)
            acc2[i][j] = (f32x4){0.f, 0.f, 0.f, 0.f};

    #pragma unroll 1
    for (int fc = 0; fc < 4; fc++) {
        f32x4 acc1[4][4];
        #pragma unroll
        for (int i = 0; i < 4; i++)
            #pragma unroll
            for (int j = 0; j < 4; j++)
                acc1[i][j] = (f32x4){0.f, 0.f, 0.f, 0.f};

        int ntb1 = fc * 16 + wc * 4;
        bf16x8 xa[4], xb[4];
        #pragma unroll
        for (int j = 0; j < 4; j++)
            xa[j] = *(const bf16x8*)&W1F[((size_t)(ntb1 + j) * 8 + 0) * 512 + lane * 8];
        #pragma unroll
        for (int k2 = 0; k2 < 8; k2 += 2) {
            if (k2 + 1 < 8) {
                #pragma unroll
                for (int j = 0; j < 4; j++)
                    xb[j] = *(const bf16x8*)&W1F[((size_t)(ntb1 + j) * 8 + k2 + 1) * 512 + lane * 8];
            }
            {
                bf16x8 ya[4];
                #pragma unroll
                for (int i = 0; i < 4; i++) {
                    int mm = i * 16 + lr;
                    ya[i] = *(const bf16x8*)&hs[k2 * 2048 + mm * 32 + (lg ^ ((mm >> 1) & 3)) * 8];
                }
                #pragma unroll
                for (int i = 0; i < 4; i++)
                    #pragma unroll
                    for (int j = 0; j < 4; j++)
                        acc1[i][j] = __builtin_amdgcn_mfma_f32_16x16x32_bf16(xa[j], ya[i], acc1[i][j], 0, 0, 0);
            }
            if (k2 + 2 < 8) {
                #pragma unroll
                for (int j = 0; j < 4; j++)
                    xa[j] = *(const bf16x8*)&W1F[((size_t)(ntb1 + j) * 8 + k2 + 2) * 512 + lane * 8];
            }
            {
                bf16x8 ya[4];
                #pragma unroll
                for (int i = 0; i < 4; i++) {
                    int mm = i * 16 + lr;
                    ya[i] = *(const bf16x8*)&hs[(k2 + 1) * 2048 + mm * 32 + (lg ^ ((mm >> 1) & 3)) * 8];
                }
                #pragma unroll
                for (int i = 0; i < 4; i++)
                    #pragma unroll
                    for (int j = 0; j < 4; j++)
                        acc1[i][j] = __builtin_amdgcn_mfma_f32_16x16x32_bf16(xb[j], ya[i], acc1[i][j], 0, 0, 0);
            }
        }

        // relu + bias -> As (window layout); As' attnout contents are dead
        __syncthreads();
        #pragma unroll
        for (int i = 0; i < 4; i++) {
            int row = i * 16 + lr;
            #pragma unroll
            for (int j = 0; j < 4; j++) {
                int ncol = wc * 64 + j * 16 + lg * 4;
                f32x4 bv = *(const f32x4*)&bf1[fc * 256 + ncol];
                int win = ncol >> 5, cw = ncol & 31;
                int p = (cw >> 3) ^ ((row >> 1) & 3);
                u16x4 ov;
                #pragma unroll
                for (int rr = 0; rr < 4; rr++)
                    ov[rr] = f2b(fmaxf(acc1[i][j][rr] + bv[rr], 0.f));
                *(u16x4*)&As[win * 2048 + row * 32 + p * 8 + (cw & 7)] = ov;
            }
        }
        __syncthreads();

        // FFN2 partial: acc2 += f1_chunk @ W2[fc]
        int ntb2 = wc * 4;
        #pragma unroll
        for (int j = 0; j < 4; j++)
            xa[j] = *(const bf16x8*)&W2F[((size_t)(ntb2 + j) * 32 + fc * 8 + 0) * 512 + lane * 8];
        #pragma unroll
        for (int k2 = 0; k2 < 8; k2 += 2) {
            if (k2 + 1 < 8) {
                #pragma unroll
                for (int j = 0; j < 4; j++)
                    xb[j] = *(const bf16x8*)&W2F[((size_t)(ntb2 + j) * 32 + fc * 8 + k2 + 1) * 512 + lane * 8];
            }
            {
                bf16x8 ya[4];
                #pragma unroll
                for (int i = 0; i < 4; i++) {
                    int mm = i * 16 + lr;
                    ya[i] = *(const bf16x8*)&As[k2 * 2048 + mm * 32 + (lg ^ ((mm >> 1) & 3)) * 8];
                }
                #pragma unroll
                for (int i = 0; i < 4; i++)
                    #pragma unroll
                    for (int j = 0; j < 4; j++)
                        acc2[i][j] = __builtin_amdgcn_mfma_f32_16x16x32_bf16(xa[j], ya[i], acc2[i][j], 0, 0, 0);
            }
            if (k2 + 2 < 8) {
                #pragma unroll
                for (int j = 0; j < 4; j++)
                    xa[j] = *(const bf16x8*)&W2F[((size_t)(ntb2 + j) * 32 + fc * 8 + k2 + 2) * 512 + lane * 8];
            }
            {
                bf16x8 ya[4];
                #pragma unroll
                for (int i = 0; i < 4; i++) {
                    int mm = i * 16 + lr;
                    ya[i] = *(const bf16x8*)&As[(k2 + 1) * 2048 + mm * 32 + (lg ^ ((mm >> 1) & 3)) * 8];
                }
                #pragma unroll
                for (int i = 0; i < 4; i++)
                    #pragma unroll
                    for (int j = 0; j < 4; j++)
                        acc2[i][j] = __builtin_amdgcn_mfma_f32_16x16x32_bf16(xb[j], ya[i], acc2[i][j], 0, 0, 0);
            }
        }
    }
    __syncthreads();

    // ---- final LN: cur = LN(acc2 + bf2 + h)*g2 + b2, residual h from hs ----
    float s1[4] = {0.f,0.f,0.f,0.f}, sq[4] = {0.f,0.f,0.f,0.f};
    #pragma unroll
    for (int i = 0; i < 4; i++) {
        int row = i * 16 + lr;
        #pragma unroll
        for (int j = 0; j < 4; j++) {
            int ncol = wc * 64 + j * 16 + lg * 4;
            f32x4 bv = *(const f32x4*)&bf2[ncol];
            int win = ncol >> 5, cw = ncol & 31;
            int p = (cw >> 3) ^ ((row >> 1) & 3);
            u16x4 rv = *(const u16x4*)&hs[win * 2048 + row * 32 + p * 8 + (cw & 7)];
            #pragma unroll
            for (int rr = 0; rr < 4; rr++) {
                acc2[i][j][rr] += bv[rr] + b2f(rv[rr]);
                s1[i] += acc2[i][j][rr];
                sq[i] += acc2[i][j][rr] * acc2[i][j][rr];
            }
        }
    }
    #pragma unroll
    for (int i = 0; i < 4; i++) {
        s1[i] += __shfl_xor(s1[i], 16);  s1[i] += __shfl_xor(s1[i], 32);
        sq[i] += __shfl_xor(sq[i], 16);  sq[i] += __shfl_xor(sq[i], 32);
        if (lg == 0) {
            int rb = i * 16 + lr;
            ssum[rb * 4 + wc] = s1[i];
            ssq[rb * 4 + wc]  = sq[i];
        }
    }
    __syncthreads();
    #pragma unroll
    for (int i = 0; i < 4; i++) {
        int rb = i * 16 + lr;
        float ts = 0.f, tq = 0.f;
        #pragma unroll
        for (int w = 0; w < 4; w++) { ts += ssum[rb * 4 + w]; tq += ssq[rb * 4 + w]; }
        float mean = ts * (1.f / 256.f);
        float var = tq * (1.f / 256.f) - mean * mean;
        float inv = rsqrtf(var + 1e-5f);
        int row = ra0 + rb;
        #pragma unroll
        for (int j = 0; j < 4; j++) {
            int ncol = wc * 64 + j * 16 + lg * 4;
            f32x4 gv = *(const f32x4*)&g2[ncol];
            f32x4 bv = *(const f32x4*)&b2[ncol];
            u16x4 ov;
            #pragma unroll
            for (int rr = 0; rr < 4; rr++)
                ov[rr] = f2b((acc2[i][j][rr] - mean) * inv * gv[rr] + bv[rr]);
            *(u16x4*)&C[(size_t)row * 256 + ncol] = ov;
        }
    }
}

// ---------------- classifier head ----------------
__global__ __launch_bounds__(256) void classifier(
    const unsigned short* __restrict__ xin,
    const float* __restrict__ Wc1, const float* __restrict__ bc1,
    const float* __restrict__ Wc2, const float* __restrict__ bc2,
    const float* __restrict__ Wc3, const float* __restrict__ bc3,
    float* __restrict__ out)
{
    __shared__ float w1[256][9];
    __shared__ float w2[64], b2s[8], w3[16], b3s[2], b1s[8];
    int t = threadIdx.x;
    #pragma unroll
    for (int i = 0; i < 8; i++) {
        int idx = t + i * 256;
        w1[idx >> 3][idx & 7] = Wc1[idx];
    }
    if (t < 64) w2[t] = Wc2[t];
    if (t < 16) w3[t] = Wc3[t];
    if (t < 8) { b2s[t] = bc2[t]; b1s[t] = bc1[t]; }
    if (t < 2) b3s[t] = bc3[t];
    __syncthreads();
    int g = t >> 3, m = t & 7;
    size_t row = (size_t)blockIdx.x * 32 + g;
    float z[8] = {0.f,0.f,0.f,0.f,0.f,0.f,0.f,0.f};
    const unsigned short* xr = xin + row * 256 + m * 32;
    #pragma unroll
    for (int cidx = 0; cidx < 4; cidx++) {
        u16x8 xv = *(const u16x8*)&xr[cidx * 8];
        #pragma unroll
        for (int e = 0; e < 8; e++) {
            float xf = b2f(xv[e]);
            int ei = m * 32 + cidx * 8 + e;
            #pragma unroll
            for (int j = 0; j < 8; j++) z[j] = fmaf(xf, w1[ei][j], z[j]);
        }
    }
    #pragma unroll
    for (int d = 1; d < 8; d <<= 1)
        #pragma unroll
        for (int j = 0; j < 8; j++) z[j] += __shfl_xor(z[j], d);
    float z1[8], z2[8];
    #pragma unroll
    for (int j = 0; j < 8; j++) z1[j] = tanhf(z[j] + b1s[j]);
    #pragma unroll
    for (int j2 = 0; j2 < 8; j2++) {
        float sacc = b2s[j2];
        #pragma unroll
        for (int j = 0; j < 8; j++) sacc = fmaf(z1[j], w2[j * 8 + j2], sacc);
        z2[j2] = tanhf(sacc);
    }
    if (m < 2) {
        float sacc = b3s[m];
        #pragma unroll
        for (int j = 0; j < 8; j++) sacc = fmaf(z2[j], w3[j * 2 + m], sacc);
        out[row * 2 + m] = 1.f / (1.f + __expf(-sacc));
    }
}

extern "C" void kernel_launch(void* const* d_in, const int* in_sizes, int n_in,
                              void* d_out, int out_size, void* d_ws, size_t ws_size,
                              hipStream_t stream) {
    const float* x        = (const float*)d_in[0];
    const float* q        = (const float*)d_in[1];
    const int*   positions= (const int*)d_in[2];
    const float* pos_emb  = (const float*)d_in[3];
    const float* Wq       = (const float*)d_in[4];
    const float* Wk       = (const float*)d_in[5];
    const float* Wv       = (const float*)d_in[6];
    const float* Wo       = (const float*)d_in[7];
    const float* bo       = (const float*)d_in[8];
    const float* g1       = (const float*)d_in[9];
    const float* b1       = (const float*)d_in[10];
    const float* g2       = (const float*)d_in[11];
    const float* b2       = (const float*)d_in[12];
    const float* Wf1      = (const float*)d_in[13];
    const float* bf1      = (const float*)d_in[14];
    const float* Wf2      = (const float*)d_in[15];
    const float* bf2      = (const float*)d_in[16];
    const float* Wc1      = (const float*)d_in[17];
    const float* bc1      = (const float*)d_in[18];
    const float* Wc2      = (const float*)d_in[19];
    const float* bc2      = (const float*)d_in[20];
    const float* Wc3      = (const float*)d_in[21];
    const float* bc3      = (const float*)d_in[22];
    float* out = (float*)d_out;

    const int R = 512 * 90;          // 46080 token rows
    char* ws = (char*)d_ws;
    size_t off = 0;
    auto alloc = [&](size_t bytes) -> void* {
        void* p = ws + off;
        off += (bytes + 255) & ~(size_t)255;
        return p;
    };
    unsigned short* cur = (unsigned short*)alloc((size_t)R * 256 * 2);
    unsigned short* qb  = (unsigned short*)alloc((size_t)R * 256 * 2);
    unsigned short* qho = (unsigned short*)alloc((size_t)R * 256 * 2);  // attn out
    unsigned short* WoF = (unsigned short*)alloc((size_t)3 * 256 * 256 * 2);
    unsigned short* W1F = (unsigned short*)alloc((size_t)3 * 1024 * 256 * 2);
    unsigned short* W2F = (unsigned short*)alloc((size_t)3 * 256 * 1024 * 2);
    unsigned short* WTqkv = (unsigned short*)alloc((size_t)3 * 3 * 1024 * 2);

    for (int l = 0; l < 3; l++) {
        prep_wfrag<<<dim3(8, 16),  256, 0, stream>>>(Wo  + (size_t)l*256*256,  WoF + (size_t)l*256*256,  256, 256);
        prep_wfrag<<<dim3(8, 64),  256, 0, stream>>>(Wf1 + (size_t)l*256*1024, W1F + (size_t)l*1024*256, 256, 1024);
        prep_wfrag<<<dim3(32, 16), 256, 0, stream>>>(Wf2 + (size_t)l*1024*256, W2F + (size_t)l*256*1024, 1024, 256);
    }
    prep_wT<<<9, 256, 0, stream>>>(Wq, Wk, Wv, WTqkv);
    add_posemb_q<<<R, 256, 0, stream>>>(x, positions, pos_emb, q, cur, qb);

    for (int l = 0; l < 3; l++) {
        attn_kernel<<<512 * 8, 384, 0, stream>>>(cur, qb, WTqkv + (size_t)l * 3 * 1024, qho);
        wo_ffn_fused<<<dim3(720), 256, 0, stream>>>(
            qho, WoF + (size_t)l*256*256, bo + l*256,
            qb, g1 + l*256, b1 + l*256,
            W1F + (size_t)l*1024*256, bf1 + l*1024,
            W2F + (size_t)l*256*1024, bf2 + l*256,
            g2 + l*256, b2 + l*256, cur);
    }
    classifier<<<R / 32, 256, 0, stream>>>(cur, Wc1, bc1, Wc2, bc2, Wc3, bc3, out);
}